// Round 2
// baseline (171.787 us; speedup 1.0000x reference)
//
#include <hip/hip_runtime.h>
#include <hip/hip_bf16.h>

// Problem: B=8, S=1024, D=256, H=8, HD=32
// Pipeline:
//   mask_prep: kv_mask (int32 OR packed bool, auto-detected) -> additive f32 mskf
//   prep:    q,Wq,Wk,Wv,Wo f32 -> bf16 in ws
//   bt_gemm: qh = q@Wq^T+bq (bf16), kh = q@Wk^T+bk (bf16)
//   bt_gemm: vt = Wv@q^T + bv (bf16, [256 ch][8192 seq])  (swapped operands -> transposed V)
//   attn:    flash attention per (b, 32-row q-tile), wave = head, bias staged via LDS
//   ln:      LayerNorm over D=256 -> bf16
//   bt_gemm: out = an@Wo^T + bo (f32) -> d_out
//
// Workspace layout (bytes):            requires ~29.1 MB of d_ws
//   0        q_bf   (4 MiB)
//   4  MiB   qh     (4 MiB)
//   8  MiB   kh     (4 MiB)
//   12 MiB   vt     (4 MiB)
//   16 MiB   a_f32  (8 MiB)
//   24 MiB   an     (4 MiB)
//   28 MiB   w_bf   (512 KiB: Wq,Wk,Wv,Wo each 65536 bf16)
//   29 MiB   mskf   (32 KiB f32)

static constexpr int SEQ = 1024;
static constexpr float SCL  = 0.17677669529663687f;  // 1/sqrt(32)
static constexpr float NEGV = -1000000000.0f;

typedef __attribute__((ext_vector_type(8))) __bf16 bf8v;
typedef __attribute__((ext_vector_type(4))) float  f4v;

__device__ __forceinline__ f4v mfma16(bf8v a, bf8v b, f4v c) {
  return __builtin_amdgcn_mfma_f32_16x16x32_bf16(a, b, c, 0, 0, 0);
}
__device__ __forceinline__ unsigned short bfbits(float f) {
  __hip_bfloat16 hbf = __float2bfloat16(f);
  unsigned short u; __builtin_memcpy(&u, &hbf, 2); return u;
}

// ---------------------------------------------------------------- mask prep
// Single block of 256 threads. Detect whether kv_mask arrived as int32
// (harness "integer -> const int*") or as packed 1-byte bools, then emit
// additive mask: 0.0 for attend, -1e9 for masked.
// Detection: read the first 8192 bytes as 2048 u32. True int32 0/1 data has
// no bits above bit0; packed random bools set upper bytes with prob ~1.
__global__ __launch_bounds__(256) void mask_prep_kernel(
    const int* __restrict__ km, float* __restrict__ mskf)
{
  __shared__ int isbool;
  int t = threadIdx.x;
  if (t == 0) isbool = 0;
  __syncthreads();
  const unsigned* u = (const unsigned*)km;
  int any = 0;
  for (int i = t; i < 2048; i += 256)
    if (u[i] & ~1u) any = 1;
  if (any) isbool = 1;   // benign race: all writers store 1
  __syncthreads();
  const unsigned char* b8 = (const unsigned char*)km;
  for (int i = t; i < 8192; i += 256) {
    int mv = isbool ? (int)b8[i] : km[i];
    mskf[i] = mv ? 0.f : NEGV;
  }
}

// ---------------------------------------------------------------- prep
__global__ __launch_bounds__(256) void prep_kernel(
    const float* __restrict__ q, const float* __restrict__ Wq,
    const float* __restrict__ Wk, const float* __restrict__ Wv,
    const float* __restrict__ Wo,
    __hip_bfloat16* __restrict__ q_bf, __hip_bfloat16* __restrict__ w_bf)
{
  const int NQ4 = (8192 * 256) / 4;   // 524288 float4 groups for q
  const int NW4 = 65536 / 4;          // 16384 per weight
  int i = blockIdx.x * 256 + threadIdx.x;
  if (i >= NQ4 + 4 * NW4) return;
  const float4* src; __hip_bfloat16* dst;
  if (i < NQ4) {
    src = (const float4*)q + i;
    dst = q_bf + (long)i * 4;
  } else {
    int j = i - NQ4; int w = j >> 14; int o4 = j & (NW4 - 1);
    const float* sp = (w == 0) ? Wq : (w == 1) ? Wk : (w == 2) ? Wv : Wo;
    src = (const float4*)sp + o4;
    dst = w_bf + w * 65536 + o4 * 4;
  }
  float4 v = *src;
  ushort4 pk;
  pk.x = bfbits(v.x); pk.y = bfbits(v.y); pk.z = bfbits(v.z); pk.w = bfbits(v.w);
  *reinterpret_cast<ushort4*>(dst) = pk;
}

// ------------------------------------------------- generic B^T GEMM (K=256)
// C[m][n] = sum_k A[m][k]*B[n][k] + bias[]   (A,B bf16 row-major, K=256)
// grid = (M/64, N/128), block = 256 (4 waves; wave w -> cols w*32..w*32+31)
template<bool OUT_F32, bool BIAS_M>
__global__ __launch_bounds__(256) void bt_gemm(
    const __hip_bfloat16* __restrict__ A, const __hip_bfloat16* __restrict__ Bm,
    const float* __restrict__ bias, void* __restrict__ outv, long ldOut)
{
  int m0 = blockIdx.x * 64;
  int w  = threadIdx.x >> 6;
  int n0 = blockIdx.y * 128 + w * 32;
  int l  = threadIdx.x & 63, lr = l & 15, lg = l >> 4;

  f4v acc[4][2];
#pragma unroll
  for (int mt = 0; mt < 4; ++mt)
#pragma unroll
    for (int nt = 0; nt < 2; ++nt) acc[mt][nt] = f4v{0.f, 0.f, 0.f, 0.f};

  const __hip_bfloat16* Ab = A  + (long)(m0 + lr) * 256 + lg * 8;
  const __hip_bfloat16* Bb = Bm + (long)(n0 + lr) * 256 + lg * 8;
#pragma unroll
  for (int k0 = 0; k0 < 256; k0 += 32) {
    bf8v af[4], bfr[2];
#pragma unroll
    for (int mt = 0; mt < 4; ++mt)
      af[mt] = *reinterpret_cast<const bf8v*>(Ab + (long)mt * 16 * 256 + k0);
#pragma unroll
    for (int nt = 0; nt < 2; ++nt)
      bfr[nt] = *reinterpret_cast<const bf8v*>(Bb + (long)nt * 16 * 256 + k0);
#pragma unroll
    for (int mt = 0; mt < 4; ++mt)
#pragma unroll
      for (int nt = 0; nt < 2; ++nt)
        acc[mt][nt] = mfma16(af[mt], bfr[nt], acc[mt][nt]);
  }

#pragma unroll
  for (int mt = 0; mt < 4; ++mt) {
    int mrow = m0 + mt * 16 + lg * 4;
#pragma unroll
    for (int nt = 0; nt < 2; ++nt) {
      int ncol = n0 + nt * 16 + lr;
#pragma unroll
      for (int r = 0; r < 4; ++r) {
        float v = acc[mt][nt][r] + (BIAS_M ? bias[mrow + r] : bias[ncol]);
        long idx = (long)(mrow + r) * ldOut + ncol;
        if constexpr (OUT_F32) ((float*)outv)[idx] = v;
        else ((__hip_bfloat16*)outv)[idx] = __float2bfloat16(v);
      }
    }
  }
}

// ---------------------------------------------------------------- attention
// grid = 256 (b*32 + qtile), block = 512 (8 waves; wave = head)
// QT=32, KT=32. Bias staged coalesced -> regs -> LDS [q][h][k] (stride-266 rows).
__global__ __launch_bounds__(512) void attn_kernel(
    const __hip_bfloat16* __restrict__ qh, const __hip_bfloat16* __restrict__ kh,
    const __hip_bfloat16* __restrict__ vt, const float* __restrict__ bias,
    const float* __restrict__ mskf, float* __restrict__ aout)
{
  __shared__ float bsm[32 * 266];                       // bias tile [q][h*33 + k]
  __shared__ __align__(16) __hip_bfloat16 psm[8][32 * 40];  // per-wave P, padded rows
  __shared__ float msm[32];                             // mask additive per k

  int bb = blockIdx.x >> 5;
  int qt = blockIdx.x & 31;
  int h  = threadIdx.x >> 6;
  int l  = threadIdx.x & 63, lr = l & 15, lg = l >> 4;
  int q0 = qt * 32;
  long bS = (long)bb * SEQ;
  int t = threadIdx.x;

  // Q fragments (held in regs for the whole k-loop)
  bf8v qf[2];
#pragma unroll
  for (int mt = 0; mt < 2; ++mt)
    qf[mt] = *reinterpret_cast<const bf8v*>(qh + (bS + q0 + mt * 16 + lr) * 256 + h * 32 + lg * 8);

  f4v o[2][2];
  float mrun[2][4], lrun[2][4];
#pragma unroll
  for (int mt = 0; mt < 2; ++mt) {
#pragma unroll
    for (int nt = 0; nt < 2; ++nt) o[mt][nt] = f4v{0.f, 0.f, 0.f, 0.f};
#pragma unroll
    for (int r = 0; r < 4; ++r) { mrun[mt][r] = -1e30f; lrun[mt][r] = 0.f; }
  }

  float4 br[4];
  auto issue = [&](int kbase) {
#pragma unroll
    for (int r2 = 0; r2 < 4; ++r2) {
      int f4i = r2 * 512 + t;
      int qq = f4i >> 6, c4 = f4i & 63;
      br[r2] = *reinterpret_cast<const float4*>(
          bias + ((bS + q0 + qq) * SEQ + kbase) * 8 + c4 * 4);
    }
  };
  issue(0);

  for (int kt = 0; kt < 32; ++kt) {
    int kbase = kt * 32;
    __syncthreads();   // previous compute done reading LDS
    // write staged bias regs -> LDS rearranged [q][h][k]
#pragma unroll
    for (int r2 = 0; r2 < 4; ++r2) {
      int f4i = r2 * 512 + t;
      int qq = f4i >> 6, c4 = f4i & 63;
      int kk = c4 >> 1, h0 = (c4 & 1) * 4;
      float vv[4] = {br[r2].x, br[r2].y, br[r2].z, br[r2].w};
#pragma unroll
      for (int ii = 0; ii < 4; ++ii)
        bsm[qq * 266 + (h0 + ii) * 33 + kk] = vv[ii];
    }
    if (t < 32) msm[t] = mskf[bS + kbase + t];
    __syncthreads();   // staging visible
    if (kt + 1 < 32) issue(kbase + 32);   // prefetch next tile into regs

    // ---- QK^T ----
    bf8v kf[2];
#pragma unroll
    for (int nt = 0; nt < 2; ++nt)
      kf[nt] = *reinterpret_cast<const bf8v*>(
          kh + (bS + kbase + nt * 16 + lr) * 256 + h * 32 + lg * 8);
    f4v s[2][2];
#pragma unroll
    for (int mt = 0; mt < 2; ++mt)
#pragma unroll
      for (int nt = 0; nt < 2; ++nt) {
        s[mt][nt] = f4v{0.f, 0.f, 0.f, 0.f};
        s[mt][nt] = mfma16(qf[mt], kf[nt], s[mt][nt]);
      }

    // ---- softmax (online), P -> LDS bf16 ----
#pragma unroll
    for (int mt = 0; mt < 2; ++mt) {
#pragma unroll
      for (int r = 0; r < 4; ++r) {
        int qq = mt * 16 + lg * 4 + r;
        float v0 = s[mt][0][r] * SCL + bsm[qq * 266 + h * 33 + lr]      + msm[lr];
        float v1 = s[mt][1][r] * SCL + bsm[qq * 266 + h * 33 + 16 + lr] + msm[16 + lr];
        float tm = fmaxf(v0, v1);
#pragma unroll
        for (int mm = 1; mm < 16; mm <<= 1) tm = fmaxf(tm, __shfl_xor(tm, mm));
        float mo = mrun[mt][r], mn = fmaxf(mo, tm);
        float al = __expf(mo - mn);
        float p0 = __expf(v0 - mn), p1 = __expf(v1 - mn);
        float ts = p0 + p1;
#pragma unroll
        for (int mm = 1; mm < 16; mm <<= 1) ts += __shfl_xor(ts, mm);
        mrun[mt][r] = mn;
        lrun[mt][r] = lrun[mt][r] * al + ts;
        o[mt][0][r] *= al; o[mt][1][r] *= al;
        psm[h][qq * 40 + lr]      = __float2bfloat16(p0);
        psm[h][qq * 40 + 16 + lr] = __float2bfloat16(p1);
      }
    }

    // ---- PV ----
    bf8v pa[2], vf[2];
#pragma unroll
    for (int mt = 0; mt < 2; ++mt)
      pa[mt] = *reinterpret_cast<const bf8v*>(&psm[h][(mt * 16 + lr) * 40 + lg * 8]);
#pragma unroll
    for (int n2 = 0; n2 < 2; ++n2)
      vf[n2] = *reinterpret_cast<const bf8v*>(
          vt + (long)(h * 32 + n2 * 16 + lr) * 8192 + bS + kbase + lg * 8);
#pragma unroll
    for (int mt = 0; mt < 2; ++mt)
#pragma unroll
      for (int n2 = 0; n2 < 2; ++n2)
        o[mt][n2] = mfma16(pa[mt], vf[n2], o[mt][n2]);
  }

  // epilogue: normalize + store f32
#pragma unroll
  for (int mt = 0; mt < 2; ++mt)
#pragma unroll
    for (int r = 0; r < 4; ++r) {
      float inv = 1.f / lrun[mt][r];
      int qq = mt * 16 + lg * 4 + r;
      long base = (bS + q0 + qq) * 256 + h * 32;
      aout[base + lr]      = o[mt][0][r] * inv;
      aout[base + 16 + lr] = o[mt][1][r] * inv;
    }
}

// ---------------------------------------------------------------- LayerNorm
// grid = 2048, block = 256 (4 waves; wave = row)
__global__ __launch_bounds__(256) void ln_kernel(
    const float* __restrict__ a, const float* __restrict__ gamma,
    const float* __restrict__ beta, __hip_bfloat16* __restrict__ an)
{
  int row = blockIdx.x * 4 + (threadIdx.x >> 6);
  int l = threadIdx.x & 63;
  const float4 v = *reinterpret_cast<const float4*>(a + (long)row * 256 + l * 4);
  float sm = v.x + v.y + v.z + v.w;
  float sq = v.x * v.x + v.y * v.y + v.z * v.z + v.w * v.w;
#pragma unroll
  for (int m = 1; m < 64; m <<= 1) { sm += __shfl_xor(sm, m); sq += __shfl_xor(sq, m); }
  float mean = sm * (1.f / 256.f);
  float var  = sq * (1.f / 256.f) - mean * mean;
  float rstd = rsqrtf(var + 1e-5f);
  float4 g  = *reinterpret_cast<const float4*>(gamma + l * 4);
  float4 bt = *reinterpret_cast<const float4*>(beta  + l * 4);
  ushort4 pk;
  pk.x = bfbits((v.x - mean) * rstd * g.x + bt.x);
  pk.y = bfbits((v.y - mean) * rstd * g.y + bt.y);
  pk.z = bfbits((v.z - mean) * rstd * g.z + bt.z);
  pk.w = bfbits((v.w - mean) * rstd * g.w + bt.w);
  *reinterpret_cast<ushort4*>(an + (long)row * 256 + l * 4) = pk;
}

// ---------------------------------------------------------------- launch
extern "C" void kernel_launch(void* const* d_in, const int* in_sizes, int n_in,
                              void* d_out, int out_size, void* d_ws, size_t ws_size,
                              hipStream_t stream) {
  const float* q   = (const float*)d_in[0];
  const int*   km  = (const int*)d_in[1];
  const float* bias = (const float*)d_in[2];
  const float* Wq = (const float*)d_in[3];
  const float* bq = (const float*)d_in[4];
  const float* Wk = (const float*)d_in[5];
  const float* bk = (const float*)d_in[6];
  const float* Wv = (const float*)d_in[7];
  const float* bv = (const float*)d_in[8];
  const float* gamma = (const float*)d_in[9];
  const float* beta  = (const float*)d_in[10];
  const float* Wo = (const float*)d_in[11];
  const float* bo = (const float*)d_in[12];

  char* wsb = (char*)d_ws;
  __hip_bfloat16* q_bf = (__hip_bfloat16*)(wsb + 0);
  __hip_bfloat16* qh   = (__hip_bfloat16*)(wsb + (4  << 20));
  __hip_bfloat16* kh   = (__hip_bfloat16*)(wsb + (8  << 20));
  __hip_bfloat16* vt   = (__hip_bfloat16*)(wsb + (12 << 20));
  float*          af   = (float*)         (wsb + (16 << 20));
  __hip_bfloat16* an   = (__hip_bfloat16*)(wsb + (24 << 20));
  __hip_bfloat16* wbf  = (__hip_bfloat16*)(wsb + (28 << 20));
  float*          mskf = (float*)         (wsb + (29 << 20));
  __hip_bfloat16* wqb = wbf, *wkb = wbf + 65536, *wvb = wbf + 131072, *wob = wbf + 196608;

  mask_prep_kernel<<<1, 256, 0, stream>>>(km, mskf);
  prep_kernel<<<2304, 256, 0, stream>>>(q, Wq, Wk, Wv, Wo, q_bf, wbf);
  bt_gemm<false, false><<<dim3(128, 2), 256, 0, stream>>>(q_bf, wqb, bq, qh, 256);
  bt_gemm<false, false><<<dim3(128, 2), 256, 0, stream>>>(q_bf, wkb, bk, kh, 256);
  bt_gemm<false, true ><<<dim3(4, 64),  256, 0, stream>>>(wvb, q_bf, bv, vt, 8192);
  attn_kernel<<<256, 512, 0, stream>>>(qh, kh, vt, bias, mskf, af);
  ln_kernel<<<2048, 256, 0, stream>>>(af, gamma, beta, an);
  bt_gemm<true, false><<<dim3(128, 2), 256, 0, stream>>>(an, wob, bo, d_out, 256);
}

// Round 3
// 158.255 us; speedup vs baseline: 1.0855x; 1.0855x over previous
//
#include <hip/hip_runtime.h>
#include <hip/hip_bf16.h>

// Problem: B=8, S=1024, D=256, H=8, HD=32
// Pipeline (3 kernels):
//   prep:      q,Wq,Wk,Wv,Wo f32 -> bf16; kv_mask (int32/bool auto) -> additive f32
//   qkv_gemm:  z=0: qh=q@Wq^T+bq, z=1: kh=q@Wk^T+bk, z=2: vt=Wv@q^T+bv (transposed V)
//   attn:      flash attention per (b, 16-row q-tile), wave=head, bias staged via LDS,
//              fused LayerNorm + out-projection (@Wo^T+bo) epilogue -> d_out (f32)
//
// Workspace layout:
//   0        q_bf   (4 MiB)
//   4  MiB   qh     (4 MiB)
//   8  MiB   kh     (4 MiB)
//   12 MiB   vt     (4 MiB)   [256 ch][8192 seq]
//   16 MiB   w_bf   (512 KiB: Wq,Wk,Wv,Wo each 65536 bf16)
//   17 MiB   mskf   (32 KiB f32)

static constexpr int SEQ = 1024;
static constexpr float SCL  = 0.17677669529663687f;  // 1/sqrt(32)
static constexpr float NEGV = -1000000000.0f;

typedef __attribute__((ext_vector_type(8))) __bf16 bf8v;
typedef __attribute__((ext_vector_type(4))) float  f4v;

__device__ __forceinline__ f4v mfma16(bf8v a, bf8v b, f4v c) {
  return __builtin_amdgcn_mfma_f32_16x16x32_bf16(a, b, c, 0, 0, 0);
}
__device__ __forceinline__ unsigned short bfbits(float f) {
  __hip_bfloat16 hbf = __float2bfloat16(f);
  unsigned short u; __builtin_memcpy(&u, &hbf, 2); return u;
}

// ---------------------------------------------------------------- prep
// blocks 0..2303: f32->bf16 of q and the 4 weights. block 2304: mask prep.
__global__ __launch_bounds__(256) void prep_kernel(
    const float* __restrict__ q, const float* __restrict__ Wq,
    const float* __restrict__ Wk, const float* __restrict__ Wv,
    const float* __restrict__ Wo, const int* __restrict__ km,
    __hip_bfloat16* __restrict__ q_bf, __hip_bfloat16* __restrict__ w_bf,
    float* __restrict__ mskf)
{
  const int NQ4 = (8192 * 256) / 4;   // 524288 float4 groups for q
  const int NW4 = 65536 / 4;          // 16384 per weight
  int t = threadIdx.x;

  if (blockIdx.x == 2304) {
    // ---- mask prep: detect int32 vs packed-bool, emit additive mask ----
    __shared__ int isbool;
    if (t == 0) isbool = 0;
    __syncthreads();
    const unsigned* u = (const unsigned*)km;
    int any = 0;
    for (int i = t; i < 2048; i += 256)
      if (u[i] & ~1u) any = 1;
    if (any) isbool = 1;   // benign race: all writers store 1
    __syncthreads();
    const unsigned char* b8 = (const unsigned char*)km;
    for (int i = t; i < 8192; i += 256) {
      int mv = isbool ? (int)b8[i] : km[i];
      mskf[i] = mv ? 0.f : NEGV;
    }
    return;
  }

  int i = blockIdx.x * 256 + t;       // < 589824 = NQ4 + 4*NW4 exactly
  const float4* src; __hip_bfloat16* dst;
  if (i < NQ4) {
    src = (const float4*)q + i;
    dst = q_bf + (long)i * 4;
  } else {
    int j = i - NQ4; int w = j >> 14; int o4 = j & (NW4 - 1);
    const float* sp = (w == 0) ? Wq : (w == 1) ? Wk : (w == 2) ? Wv : Wo;
    src = (const float4*)sp + o4;
    dst = w_bf + w * 65536 + o4 * 4;
  }
  float4 v = *src;
  ushort4 pk;
  pk.x = bfbits(v.x); pk.y = bfbits(v.y); pk.z = bfbits(v.z); pk.w = bfbits(v.w);
  *reinterpret_cast<ushort4*>(dst) = pk;
}

// ------------------------------------------------- fused QKV GEMM (K=256)
// grid (128, 2, 3), block 256 (4 waves). C[m][n] = sum_k A[m][k]*B[n][k] + bias
//   z=0: A=q_bf (8192xK), B=Wq, out=qh  [8192][256]
//   z=1: A=q_bf,          B=Wk, out=kh  [8192][256]
//   z=2: A=Wv (256xK),    B=q_bf (8192xK), out=vt [256][8192]  (bias over m)
__global__ __launch_bounds__(256) void qkv_gemm(
    const __hip_bfloat16* __restrict__ q_bf, const __hip_bfloat16* __restrict__ w_bf,
    const float* __restrict__ bq, const float* __restrict__ bk,
    const float* __restrict__ bv,
    __hip_bfloat16* __restrict__ qh, __hip_bfloat16* __restrict__ kh,
    __hip_bfloat16* __restrict__ vt)
{
  int z = blockIdx.z;
  int w = threadIdx.x >> 6;
  int l = threadIdx.x & 63, lr = l & 15, lg = l >> 4;

  const __hip_bfloat16 *A, *Bm; const float* bias; __hip_bfloat16* out;
  long ldOut; int m0, n0;
  if (z < 2) {
    A = q_bf; Bm = w_bf + z * 65536; bias = z ? bk : bq; out = z ? kh : qh;
    ldOut = 256;
    m0 = blockIdx.x * 64; n0 = blockIdx.y * 128 + w * 32;
  } else {
    A = w_bf + 2 * 65536; Bm = q_bf; bias = bv; out = vt; ldOut = 8192;
    int bid = blockIdx.y * 128 + blockIdx.x;      // 0..255
    m0 = (bid >> 6) * 64; n0 = (bid & 63) * 128 + w * 32;
  }

  f4v acc[4][2];
#pragma unroll
  for (int mt = 0; mt < 4; ++mt)
#pragma unroll
    for (int nt = 0; nt < 2; ++nt) acc[mt][nt] = f4v{0.f, 0.f, 0.f, 0.f};

  const __hip_bfloat16* Ab = A  + (long)(m0 + lr) * 256 + lg * 8;
  const __hip_bfloat16* Bb = Bm + (long)(n0 + lr) * 256 + lg * 8;
#pragma unroll
  for (int k0 = 0; k0 < 256; k0 += 32) {
    bf8v af[4], bfr[2];
#pragma unroll
    for (int mt = 0; mt < 4; ++mt)
      af[mt] = *reinterpret_cast<const bf8v*>(Ab + (long)mt * 16 * 256 + k0);
#pragma unroll
    for (int nt = 0; nt < 2; ++nt)
      bfr[nt] = *reinterpret_cast<const bf8v*>(Bb + (long)nt * 16 * 256 + k0);
#pragma unroll
    for (int mt = 0; mt < 4; ++mt)
#pragma unroll
      for (int nt = 0; nt < 2; ++nt)
        acc[mt][nt] = mfma16(af[mt], bfr[nt], acc[mt][nt]);
  }

#pragma unroll
  for (int mt = 0; mt < 4; ++mt) {
    int mrow = m0 + mt * 16 + lg * 4;
#pragma unroll
    for (int nt = 0; nt < 2; ++nt) {
      int ncol = n0 + nt * 16 + lr;
#pragma unroll
      for (int r = 0; r < 4; ++r) {
        float v = acc[mt][nt][r] + ((z == 2) ? bias[mrow + r] : bias[ncol]);
        out[(long)(mrow + r) * ldOut + ncol] = __float2bfloat16(v);
      }
    }
  }
}

// ---------------------------------------------------------------- attention
// grid = 512 (b*64 + qtile), block = 512 (8 waves; wave = head). QT=16, KT=32.
// Fused epilogue: LayerNorm over D=256 + out = an@Wo^T + bo -> d_out (f32).
__global__ __launch_bounds__(512) void attn_kernel(
    const __hip_bfloat16* __restrict__ qh, const __hip_bfloat16* __restrict__ kh,
    const __hip_bfloat16* __restrict__ vt, const float* __restrict__ bias,
    const float* __restrict__ mskf, const __hip_bfloat16* __restrict__ wob,
    const float* __restrict__ gamma, const float* __restrict__ beta,
    const float* __restrict__ bo, float* __restrict__ outp)
{
  __shared__ float bsm[16 * 266];                          // bias tile [q][h*33+k]
  __shared__ __align__(16) __hip_bfloat16 psm[8][16 * 40]; // per-wave P
  __shared__ float msm[32];                                // additive mask per k
  __shared__ float osm[16 * 261];                          // attn out f32 [q][d]
  __shared__ __align__(16) __hip_bfloat16 ansm[16 * 264];  // LN out bf16 [q][d]

  int bb = blockIdx.x >> 6;
  int qt = blockIdx.x & 63;
  int h  = threadIdx.x >> 6;
  int l  = threadIdx.x & 63, lr = l & 15, lg = l >> 4;
  int q0 = qt * 16;
  long bS = (long)bb * SEQ;
  int t = threadIdx.x;

  bf8v qf = *reinterpret_cast<const bf8v*>(qh + (bS + q0 + lr) * 256 + h * 32 + lg * 8);

  f4v o[2];
  float mrun[4], lrun[4];
#pragma unroll
  for (int nt = 0; nt < 2; ++nt) o[nt] = f4v{0.f, 0.f, 0.f, 0.f};
#pragma unroll
  for (int r = 0; r < 4; ++r) { mrun[r] = -1e30f; lrun[r] = 0.f; }

  float4 br[2];
  auto issue = [&](int kbase) {
#pragma unroll
    for (int r2 = 0; r2 < 2; ++r2) {
      int f4i = r2 * 512 + t;
      int qq = f4i >> 6, c4 = f4i & 63;
      br[r2] = *reinterpret_cast<const float4*>(
          bias + ((bS + q0 + qq) * SEQ + kbase) * 8 + c4 * 4);
    }
  };
  issue(0);

  for (int kt = 0; kt < 32; ++kt) {
    int kbase = kt * 32;
    __syncthreads();   // previous compute done reading LDS
#pragma unroll
    for (int r2 = 0; r2 < 2; ++r2) {
      int f4i = r2 * 512 + t;
      int qq = f4i >> 6, c4 = f4i & 63;
      int kk = c4 >> 1, h0 = (c4 & 1) * 4;
      float vv[4] = {br[r2].x, br[r2].y, br[r2].z, br[r2].w};
#pragma unroll
      for (int ii = 0; ii < 4; ++ii)
        bsm[qq * 266 + (h0 + ii) * 33 + kk] = vv[ii];
    }
    if (t < 32) msm[t] = mskf[bS + kbase + t];
    __syncthreads();   // staging visible
    if (kt + 1 < 32) issue(kbase + 32);   // prefetch next bias tile into regs

    // K and V tile loads issued early (latency hides under QK^T + softmax)
    bf8v kf[2], vf[2];
#pragma unroll
    for (int nt = 0; nt < 2; ++nt)
      kf[nt] = *reinterpret_cast<const bf8v*>(
          kh + (bS + kbase + nt * 16 + lr) * 256 + h * 32 + lg * 8);
#pragma unroll
    for (int n2 = 0; n2 < 2; ++n2)
      vf[n2] = *reinterpret_cast<const bf8v*>(
          vt + (long)(h * 32 + n2 * 16 + lr) * 8192 + bS + kbase + lg * 8);

    // ---- QK^T ----
    f4v s[2];
#pragma unroll
    for (int nt = 0; nt < 2; ++nt) {
      s[nt] = f4v{0.f, 0.f, 0.f, 0.f};
      s[nt] = mfma16(qf, kf[nt], s[nt]);
    }

    // ---- softmax (online), P -> LDS bf16 ----
#pragma unroll
    for (int r = 0; r < 4; ++r) {
      int qq = lg * 4 + r;
      float v0 = s[0][r] * SCL + bsm[qq * 266 + h * 33 + lr]      + msm[lr];
      float v1 = s[1][r] * SCL + bsm[qq * 266 + h * 33 + 16 + lr] + msm[16 + lr];
      float tm = fmaxf(v0, v1);
#pragma unroll
      for (int mm = 1; mm < 16; mm <<= 1) tm = fmaxf(tm, __shfl_xor(tm, mm));
      float mo = mrun[r], mn = fmaxf(mo, tm);
      float al = __expf(mo - mn);
      float p0 = __expf(v0 - mn), p1 = __expf(v1 - mn);
      float ts = p0 + p1;
#pragma unroll
      for (int mm = 1; mm < 16; mm <<= 1) ts += __shfl_xor(ts, mm);
      mrun[r] = mn;
      lrun[r] = lrun[r] * al + ts;
      o[0][r] *= al; o[1][r] *= al;
      psm[h][qq * 40 + lr]      = __float2bfloat16(p0);
      psm[h][qq * 40 + 16 + lr] = __float2bfloat16(p1);
    }

    // ---- PV ----
    bf8v pa = *reinterpret_cast<const bf8v*>(&psm[h][lr * 40 + lg * 8]);
#pragma unroll
    for (int n2 = 0; n2 < 2; ++n2)
      o[n2] = mfma16(pa, vf[n2], o[n2]);
  }

  // ---- epilogue: stage normalized attn-out, LayerNorm, out-projection ----
  __syncthreads();
#pragma unroll
  for (int r = 0; r < 4; ++r) {
    float inv = 1.f / lrun[r];
    int qq = lg * 4 + r;
    osm[qq * 261 + h * 32 + lr]      = o[0][r] * inv;
    osm[qq * 261 + h * 32 + 16 + lr] = o[1][r] * inv;
  }
  __syncthreads();

  // LayerNorm: 32 threads per row (half-wave), 8 elems per thread
  {
    int row = t >> 5;
    int c8 = (t & 31) * 8;
    float vv[8]; float sm = 0.f, sq = 0.f;
#pragma unroll
    for (int j = 0; j < 8; ++j) {
      vv[j] = osm[row * 261 + c8 + j];
      sm += vv[j]; sq += vv[j] * vv[j];
    }
#pragma unroll
    for (int mm = 1; mm < 32; mm <<= 1) { sm += __shfl_xor(sm, mm); sq += __shfl_xor(sq, mm); }
    float mean = sm * (1.f / 256.f);
    float var  = sq * (1.f / 256.f) - mean * mean;
    float rstd = rsqrtf(var + 1e-5f);
    float4 g0 = *reinterpret_cast<const float4*>(gamma + c8);
    float4 g1 = *reinterpret_cast<const float4*>(gamma + c8 + 4);
    float4 b0 = *reinterpret_cast<const float4*>(beta + c8);
    float4 b1 = *reinterpret_cast<const float4*>(beta + c8 + 4);
    float gg[8] = {g0.x, g0.y, g0.z, g0.w, g1.x, g1.y, g1.z, g1.w};
    float bb8[8] = {b0.x, b0.y, b0.z, b0.w, b1.x, b1.y, b1.z, b1.w};
    ushort4 pkA, pkB;
    pkA.x = bfbits((vv[0] - mean) * rstd * gg[0] + bb8[0]);
    pkA.y = bfbits((vv[1] - mean) * rstd * gg[1] + bb8[1]);
    pkA.z = bfbits((vv[2] - mean) * rstd * gg[2] + bb8[2]);
    pkA.w = bfbits((vv[3] - mean) * rstd * gg[3] + bb8[3]);
    pkB.x = bfbits((vv[4] - mean) * rstd * gg[4] + bb8[4]);
    pkB.y = bfbits((vv[5] - mean) * rstd * gg[5] + bb8[5]);
    pkB.z = bfbits((vv[6] - mean) * rstd * gg[6] + bb8[6]);
    pkB.w = bfbits((vv[7] - mean) * rstd * gg[7] + bb8[7]);
    *reinterpret_cast<ushort4*>(&ansm[row * 264 + c8])     = pkA;
    *reinterpret_cast<ushort4*>(&ansm[row * 264 + c8 + 4]) = pkB;
  }
  __syncthreads();

  // out-projection: 16x256 @ Wo^T(256x256), wave h covers cols h*32..h*32+31
  f4v acc2[2];
  acc2[0] = f4v{0.f, 0.f, 0.f, 0.f}; acc2[1] = f4v{0.f, 0.f, 0.f, 0.f};
#pragma unroll
  for (int k0 = 0; k0 < 256; k0 += 32) {
    bf8v afr = *reinterpret_cast<const bf8v*>(&ansm[lr * 264 + lg * 8 + k0]);
#pragma unroll
    for (int nt = 0; nt < 2; ++nt) {
      bf8v bfrg = *reinterpret_cast<const bf8v*>(
          wob + (long)(h * 32 + nt * 16 + lr) * 256 + lg * 8 + k0);
      acc2[nt] = mfma16(afr, bfrg, acc2[nt]);
    }
  }
#pragma unroll
  for (int nt = 0; nt < 2; ++nt) {
    int ocol = h * 32 + nt * 16 + lr;
    float bov = bo[ocol];
#pragma unroll
    for (int r = 0; r < 4; ++r) {
      int orow = q0 + lg * 4 + r;
      outp[(bS + orow) * 256 + ocol] = acc2[nt][r] + bov;
    }
  }
}

// ---------------------------------------------------------------- launch
extern "C" void kernel_launch(void* const* d_in, const int* in_sizes, int n_in,
                              void* d_out, int out_size, void* d_ws, size_t ws_size,
                              hipStream_t stream) {
  const float* q   = (const float*)d_in[0];
  const int*   km  = (const int*)d_in[1];
  const float* bias = (const float*)d_in[2];
  const float* Wq = (const float*)d_in[3];
  const float* bq = (const float*)d_in[4];
  const float* Wk = (const float*)d_in[5];
  const float* bk = (const float*)d_in[6];
  const float* Wv = (const float*)d_in[7];
  const float* bv = (const float*)d_in[8];
  const float* gamma = (const float*)d_in[9];
  const float* beta  = (const float*)d_in[10];
  const float* Wo = (const float*)d_in[11];
  const float* bo = (const float*)d_in[12];

  char* wsb = (char*)d_ws;
  __hip_bfloat16* q_bf = (__hip_bfloat16*)(wsb + 0);
  __hip_bfloat16* qh   = (__hip_bfloat16*)(wsb + (4  << 20));
  __hip_bfloat16* kh   = (__hip_bfloat16*)(wsb + (8  << 20));
  __hip_bfloat16* vt   = (__hip_bfloat16*)(wsb + (12 << 20));
  __hip_bfloat16* wbf  = (__hip_bfloat16*)(wsb + (16 << 20));
  float*          mskf = (float*)         (wsb + (17 << 20));
  __hip_bfloat16* wob  = wbf + 196608;

  prep_kernel<<<2305, 256, 0, stream>>>(q, Wq, Wk, Wv, Wo, km, q_bf, wbf, mskf);
  qkv_gemm<<<dim3(128, 2, 3), 256, 0, stream>>>(q_bf, wbf, bq, bk, bv, qh, kh, vt);
  attn_kernel<<<512, 512, 0, stream>>>(qh, kh, vt, bias, mskf, wob,
                                       gamma, beta, bo, (float*)d_out);
}